// Round 1
// baseline (264.779 us; speedup 1.0000x reference)
//
#include <hip/hip_runtime.h>

// Problem: dist[N,K] = ||feat_n||^2 + ||cent_k||^2 - 2 feat . cent
// N=16384 feat rows, K=2048 centroids, D=1024. fp32 in/out.
// Strategy: bf16 MFMA GEMM (m97 structure: 128x128 tile, BK=32,
// global_load_lds width=16), fp32 norms computed exactly in prep pass.

#define MROWS 16384
#define NCOLS 2048
#define DDIM  1024
#define BM 128
#define BN 128
#define BK 32

typedef unsigned short u16;
typedef unsigned int   u32;
typedef __attribute__((ext_vector_type(8))) short          short8;
typedef __attribute__((ext_vector_type(4))) float          float4v;
typedef __attribute__((ext_vector_type(4))) unsigned short ushort4v;

__device__ __forceinline__ u16 f32_to_bf16_rne(float f) {
  u32 u = __float_as_uint(f);
  u32 r = u + 0x7FFFu + ((u >> 16) & 1u);   // round-to-nearest-even
  return (u16)(r >> 16);
}

// One block per row of D=1024 floats: convert to bf16 + exact fp32 row norm.
__global__ void prep_bf16_rows(const float* __restrict__ in, u16* __restrict__ outb,
                               float* __restrict__ sq) {
  const int row = blockIdx.x;
  const int t   = threadIdx.x;   // 256 threads * 4 floats = 1024
  const float4v v = ((const float4v*)(in + (size_t)row * DDIM))[t];
  ushort4v o;
  o[0] = f32_to_bf16_rne(v[0]);
  o[1] = f32_to_bf16_rne(v[1]);
  o[2] = f32_to_bf16_rne(v[2]);
  o[3] = f32_to_bf16_rne(v[3]);
  ((ushort4v*)(outb + (size_t)row * DDIM))[t] = o;
  float s = v[0]*v[0] + v[1]*v[1] + v[2]*v[2] + v[3]*v[3];
  #pragma unroll
  for (int off = 32; off > 0; off >>= 1) s += __shfl_down(s, off, 64);
  __shared__ float part[4];
  if ((t & 63) == 0) part[t >> 6] = s;
  __syncthreads();
  if (t == 0) sq[row] = part[0] + part[1] + part[2] + part[3];
}

__device__ __forceinline__ void load_lds16(const u16* g, u16* l) {
  __builtin_amdgcn_global_load_lds(
      (const __attribute__((address_space(1))) u32*)g,
      (__attribute__((address_space(3))) u32*)l, 16, 0, 0);
}

// C = A[M,D] * B[K,D]^T, epilogue dist = asq[m] + bsq[n] - 2*C.
// grid (NCOLS/BN, MROWS/BM), block 256 = 4 waves (2x2), wave does 64x64.
__global__ void dist_gemm(const u16* __restrict__ A, const u16* __restrict__ B,
                          const float* __restrict__ asq, const float* __restrict__ bsq,
                          float* __restrict__ out) {
  // Unpadded: global_load_lds writes wave-uniform base + lane*16 contiguously.
  __shared__ __align__(16) u16 sA[BM * BK];   // 8 KB
  __shared__ __align__(16) u16 sB[BN * BK];   // 8 KB

  const int tid  = threadIdx.x;
  const int lane = tid & 63;
  const int wave = tid >> 6;        // 0..3
  const int quad = lane >> 4;       // 0..3
  const int l16  = lane & 15;
  const int waveM = wave >> 1;      // 0..1
  const int waveN = wave & 1;       // 0..1

  const int rowBase = blockIdx.y * BM;
  const int colBase = blockIdx.x * BN;

  float4v acc[4][4];
  #pragma unroll
  for (int i = 0; i < 4; ++i)
    #pragma unroll
    for (int j = 0; j < 4; ++j)
      acc[i][j] = (float4v)(0.0f);

  for (int k0 = 0; k0 < DDIM; k0 += BK) {
    // Stage tiles: 512 chunks of 16B per tile; 2 chunks/thread/tile.
    // chunk c -> row = c>>2, kchunk = c&3; lds byte offset = c*16.
    // Per wave, c = p*256 + wave*64 + lane: lane-contiguous LDS. [required]
    #pragma unroll
    for (int p = 0; p < 2; ++p) {
      const int c   = p * 256 + tid;
      const int r   = c >> 2;
      const int kc  = c & 3;
      load_lds16(A + (size_t)(rowBase + r) * DDIM + k0 + kc * 8, sA + c * 8);
      load_lds16(B + (size_t)(colBase + r) * DDIM + k0 + kc * 8, sB + c * 8);
    }
    __syncthreads();   // compiler emits s_waitcnt vmcnt(0) before s_barrier

    short8 a[4], b[4];
    #pragma unroll
    for (int i = 0; i < 4; ++i) {
      // A-frag: A[m=l16][k=quad*8+j]  (verified layout, m120)
      a[i] = *(const short8*)&sA[(waveM * 64 + i * 16 + l16) * BK + quad * 8];
      // B-frag (B^T gemm): centers row n=l16, same k packing (m92/m97)
      b[i] = *(const short8*)&sB[(waveN * 64 + i * 16 + l16) * BK + quad * 8];
    }
    #pragma unroll
    for (int i = 0; i < 4; ++i)
      #pragma unroll
      for (int j = 0; j < 4; ++j)
        acc[i][j] = __builtin_amdgcn_mfma_f32_16x16x32_bf16(a[i], b[j], acc[i][j], 0, 0, 0);
    __syncthreads();   // before overwriting LDS next iter
  }

  // Epilogue. C/D layout: col = lane&15, row = quad*4 + reg (m89/m91 verified).
  #pragma unroll
  for (int i = 0; i < 4; ++i) {
    #pragma unroll
    for (int j = 0; j < 4; ++j) {
      const int col = colBase + waveN * 64 + j * 16 + l16;
      const float bs = bsq[col];
      #pragma unroll
      for (int r = 0; r < 4; ++r) {
        const int row = rowBase + waveM * 64 + i * 16 + quad * 4 + r;
        out[(size_t)row * NCOLS + col] = asq[row] + bs - 2.0f * acc[i][j][r];
      }
    }
  }
}

// Safety net only (ws too small): plain fp32, correct but slow.
__global__ void naive_dist(const float* __restrict__ feat, const float* __restrict__ cent,
                           float* __restrict__ out) {
  const int k = blockIdx.x * 16 + threadIdx.x;
  const int n = blockIdx.y * 16 + threadIdx.y;
  const float* fp = feat + (size_t)n * DDIM;
  const float* cp = cent + (size_t)k * DDIM;
  float s = 0.f;
  for (int d = 0; d < DDIM; ++d) { float df = fp[d] - cp[d]; s += df * df; }
  out[(size_t)n * NCOLS + k] = s;
}

extern "C" void kernel_launch(void* const* d_in, const int* in_sizes, int n_in,
                              void* d_out, int out_size, void* d_ws, size_t ws_size,
                              hipStream_t stream) {
  const float* feat    = (const float*)d_in[0];   // [16384, 1024]
  const float* centers = (const float*)d_in[1];   // [2048, 1024]
  float* out = (float*)d_out;                     // [16384, 2048]

  const size_t offA   = 0;
  const size_t offB   = (size_t)MROWS * DDIM * 2;            // 33,554,432
  const size_t offAsq = offB + (size_t)NCOLS * DDIM * 2;     // 37,748,736
  const size_t offBsq = offAsq + (size_t)MROWS * 4;          // 37,814,272
  const size_t need   = offBsq + (size_t)NCOLS * 4;          // ~37.8 MB

  if (ws_size < need) {
    dim3 grid(NCOLS / 16, MROWS / 16), block(16, 16);
    naive_dist<<<grid, block, 0, stream>>>(feat, centers, out);
    return;
  }

  u16*   Ab  = (u16*)((char*)d_ws + offA);
  u16*   Bb  = (u16*)((char*)d_ws + offB);
  float* asq = (float*)((char*)d_ws + offAsq);
  float* bsq = (float*)((char*)d_ws + offBsq);

  prep_bf16_rows<<<MROWS, 256, 0, stream>>>(feat, Ab, asq);
  prep_bf16_rows<<<NCOLS, 256, 0, stream>>>(centers, Bb, bsq);

  dim3 grid(NCOLS / BN, MROWS / BM);   // (16, 128)
  dist_gemm<<<grid, 256, 0, stream>>>(Ab, Bb, asq, bsq, out);
}

// Round 2
// 262.679 us; speedup vs baseline: 1.0080x; 1.0080x over previous
//
#include <hip/hip_runtime.h>

// dist[N,K] = ||feat_n||^2 + ||cent_k||^2 - 2 feat . cent
// N=16384, K=2048, D=1024, fp32 in/out.
// bf16 MFMA GEMM (128x128 tile, BK=32, global_load_lds width=16) with
// XOR-swizzled LDS (kills 8-way bank conflicts) + XCD-aware block remap.
// Prep: single fused kernel, one wave per row, no LDS/barrier.

#define MROWS 16384
#define NCOLS 2048
#define DDIM  1024
#define BM 128
#define BN 128
#define BK 32

typedef unsigned short u16;
typedef unsigned int   u32;
typedef __attribute__((ext_vector_type(8))) short          short8;
typedef __attribute__((ext_vector_type(8))) unsigned short ushort8;
typedef __attribute__((ext_vector_type(4))) float          float4v;

__device__ __forceinline__ u16 f32_to_bf16_rne(float f) {
  u32 u = __float_as_uint(f);
  u32 r = u + 0x7FFFu + ((u >> 16) & 1u);   // round-to-nearest-even
  return (u16)(r >> 16);
}

// One WAVE per row: convert 1024 floats -> bf16 (16B stores) + exact fp32 norm.
// No LDS, no __syncthreads. Rows 0..MROWS-1 = feat, rest = centers.
__global__ void prep_all(const float* __restrict__ feat, const float* __restrict__ cent,
                         u16* __restrict__ Ab, u16* __restrict__ Bb,
                         float* __restrict__ asq, float* __restrict__ bsq) {
  const int lane = threadIdx.x & 63;
  const int row  = (blockIdx.x * blockDim.x + threadIdx.x) >> 6;  // global wave id
  const float* src; u16* dst; float* sq;
  if (row < MROWS) {
    src = feat + (size_t)row * DDIM; dst = Ab + (size_t)row * DDIM; sq = asq + row;
  } else {
    const int r = row - MROWS;
    src = cent + (size_t)r * DDIM;   dst = Bb + (size_t)r * DDIM;  sq = bsq + r;
  }
  float s = 0.f;
  #pragma unroll
  for (int h = 0; h < 2; ++h) {
    const int base = h * 512 + lane * 8;          // 8 consecutive floats per lane
    const float4v v0 = *(const float4v*)(src + base);
    const float4v v1 = *(const float4v*)(src + base + 4);
    ushort8 o;
    o[0] = f32_to_bf16_rne(v0[0]); o[1] = f32_to_bf16_rne(v0[1]);
    o[2] = f32_to_bf16_rne(v0[2]); o[3] = f32_to_bf16_rne(v0[3]);
    o[4] = f32_to_bf16_rne(v1[0]); o[5] = f32_to_bf16_rne(v1[1]);
    o[6] = f32_to_bf16_rne(v1[2]); o[7] = f32_to_bf16_rne(v1[3]);
    *(ushort8*)(dst + base) = o;                  // 16B store
    s += v0[0]*v0[0] + v0[1]*v0[1] + v0[2]*v0[2] + v0[3]*v0[3]
       + v1[0]*v1[0] + v1[1]*v1[1] + v1[2]*v1[2] + v1[3]*v1[3];
  }
  #pragma unroll
  for (int off = 32; off > 0; off >>= 1) s += __shfl_down(s, off, 64);
  if (lane == 0) *sq = s;
}

__device__ __forceinline__ void load_lds16(const u16* g, u16* l) {
  __builtin_amdgcn_global_load_lds(
      (const __attribute__((address_space(1))) u32*)g,
      (__attribute__((address_space(3))) u32*)l, 16, 0, 0);
}

// C = A[M,D] * B[K,D]^T, epilogue dist = asq[m] + bsq[n] - 2*C.
// LDS layout XOR-swizzled: global (row r, kchunk kc) lives at LDS chunk
// r*4 + (kc ^ ((r>>1)&3)); 16B chunks. Staging permutes the SOURCE address
// (LDS dest stays lane-contiguous as global_load_lds requires); reads then
// hit each 8-entry bank-group exactly 2-way (free, m136).
__global__ void dist_gemm(const u16* __restrict__ A, const u16* __restrict__ B,
                          const float* __restrict__ asq, const float* __restrict__ bsq,
                          float* __restrict__ out) {
  __shared__ __align__(16) u16 sA[BM * BK];   // 8 KB
  __shared__ __align__(16) u16 sB[BN * BK];   // 8 KB

  const int tid  = threadIdx.x;
  const int lane = tid & 63;
  const int wave = tid >> 6;        // 0..3
  const int quad = lane >> 4;       // 0..3
  const int l16  = lane & 15;
  const int sw   = (l16 >> 1) & 3;  // row-swizzle term (row%8)>>1, i-independent
  const int waveM = wave >> 1;      // 0..1
  const int waveN = wave & 1;       // 0..1

  // XCD-aware remap: all 16 col-blocks of a row-panel land on one XCD
  // (default assignment is linear_id % 8). 128 panels -> 16 per XCD.
  const int l   = blockIdx.y * gridDim.x + blockIdx.x;  // 0..2047
  const int xcd = l & 7;
  const int j   = l >> 3;                               // 0..255
  const int by  = xcd * 16 + (j >> 4);                  // row panel
  const int bx  = j & 15;                               // col panel (fastest)
  const int rowBase = by * BM;
  const int colBase = bx * BN;

  float4v acc[4][4];
  #pragma unroll
  for (int i = 0; i < 4; ++i)
    #pragma unroll
    for (int jj = 0; jj < 4; ++jj)
      acc[i][jj] = (float4v)(0.0f);

  for (int k0 = 0; k0 < DDIM; k0 += BK) {
    #pragma unroll
    for (int p = 0; p < 2; ++p) {
      const int c  = p * 256 + tid;             // LDS chunk index (lane-contig)
      const int r  = c >> 2;
      const int kc = (c & 3) ^ ((r >> 1) & 3);  // swizzled global kchunk
      load_lds16(A + (size_t)(rowBase + r) * DDIM + k0 + kc * 8, sA + c * 8);
      load_lds16(B + (size_t)(colBase + r) * DDIM + k0 + kc * 8, sB + c * 8);
    }
    __syncthreads();

    short8 a[4], b[4];
    #pragma unroll
    for (int i = 0; i < 4; ++i) {
      const int rowA = waveM * 64 + i * 16 + l16;
      a[i] = *(const short8*)&sA[(rowA * 4 + (quad ^ sw)) * 8];
      const int rowB = waveN * 64 + i * 16 + l16;
      b[i] = *(const short8*)&sB[(rowB * 4 + (quad ^ sw)) * 8];
    }
    #pragma unroll
    for (int i = 0; i < 4; ++i)
      #pragma unroll
      for (int jj = 0; jj < 4; ++jj)
        acc[i][jj] = __builtin_amdgcn_mfma_f32_16x16x32_bf16(a[i], b[jj], acc[i][jj], 0, 0, 0);
    __syncthreads();
  }

  // Epilogue. C/D layout: col = lane&15, row = quad*4 + reg (m89/m91).
  #pragma unroll
  for (int i = 0; i < 4; ++i) {
    #pragma unroll
    for (int jj = 0; jj < 4; ++jj) {
      const int col = colBase + waveN * 64 + jj * 16 + l16;
      const float bs = bsq[col];
      #pragma unroll
      for (int r = 0; r < 4; ++r) {
        const int row = rowBase + waveM * 64 + i * 16 + quad * 4 + r;
        out[(size_t)row * NCOLS + col] = asq[row] + bs - 2.0f * acc[i][jj][r];
      }
    }
  }
}

// Safety net only (ws too small): plain fp32, correct but slow.
__global__ void naive_dist(const float* __restrict__ feat, const float* __restrict__ cent,
                           float* __restrict__ out) {
  const int k = blockIdx.x * 16 + threadIdx.x;
  const int n = blockIdx.y * 16 + threadIdx.y;
  const float* fp = feat + (size_t)n * DDIM;
  const float* cp = cent + (size_t)k * DDIM;
  float s = 0.f;
  for (int d = 0; d < DDIM; ++d) { float df = fp[d] - cp[d]; s += df * df; }
  out[(size_t)n * NCOLS + k] = s;
}

extern "C" void kernel_launch(void* const* d_in, const int* in_sizes, int n_in,
                              void* d_out, int out_size, void* d_ws, size_t ws_size,
                              hipStream_t stream) {
  const float* feat    = (const float*)d_in[0];   // [16384, 1024]
  const float* centers = (const float*)d_in[1];   // [2048, 1024]
  float* out = (float*)d_out;                     // [16384, 2048]

  const size_t offA   = 0;
  const size_t offB   = (size_t)MROWS * DDIM * 2;            // 33,554,432
  const size_t offAsq = offB + (size_t)NCOLS * DDIM * 2;     // 37,748,736
  const size_t offBsq = offAsq + (size_t)MROWS * 4;          // 37,814,272
  const size_t need   = offBsq + (size_t)NCOLS * 4;          // ~37.8 MB

  if (ws_size < need) {
    dim3 grid(NCOLS / 16, MROWS / 16), block(16, 16);
    naive_dist<<<grid, block, 0, stream>>>(feat, centers, out);
    return;
  }

  u16*   Ab  = (u16*)((char*)d_ws + offA);
  u16*   Bb  = (u16*)((char*)d_ws + offB);
  float* asq = (float*)((char*)d_ws + offAsq);
  float* bsq = (float*)((char*)d_ws + offBsq);

  // (MROWS + NCOLS) rows, one wave per row, 4 waves per block.
  prep_all<<<(MROWS + NCOLS) / 4, 256, 0, stream>>>(feat, centers, Ab, Bb, asq, bsq);

  dim3 grid(NCOLS / BN, MROWS / BM);   // (16, 128)
  dist_gemm<<<grid, 256, 0, stream>>>(Ab, Bb, asq, bsq, out);
}

// Round 3
// 250.104 us; speedup vs baseline: 1.0587x; 1.0503x over previous
//
#include <hip/hip_runtime.h>

// dist[N,K] = ||feat_n||^2 + ||cent_k||^2 - 2 feat . cent
// N=16384, K=2048, D=1024, fp32 in/out.
// bf16 MFMA GEMM: 128x128 tile, BK=64 (32 MFMA per barrier pair, halves the
// vmcnt(0)-drain count vs BK=32), global_load_lds width=16, XOR bank swizzle,
// XCD-aware block remap. Prep: one wave per row, no LDS/barrier.

#define MROWS 16384
#define NCOLS 2048
#define DDIM  1024
#define BM 128
#define BN 128
#define BK 64

typedef unsigned short u16;
typedef unsigned int   u32;
typedef __attribute__((ext_vector_type(8))) short          short8;
typedef __attribute__((ext_vector_type(8))) unsigned short ushort8;
typedef __attribute__((ext_vector_type(4))) float          float4v;

__device__ __forceinline__ u16 f32_to_bf16_rne(float f) {
  u32 u = __float_as_uint(f);
  u32 r = u + 0x7FFFu + ((u >> 16) & 1u);   // round-to-nearest-even
  return (u16)(r >> 16);
}

// One WAVE per row: convert 1024 floats -> bf16 (16B stores) + exact fp32 norm.
__global__ void prep_all(const float* __restrict__ feat, const float* __restrict__ cent,
                         u16* __restrict__ Ab, u16* __restrict__ Bb,
                         float* __restrict__ asq, float* __restrict__ bsq) {
  const int lane = threadIdx.x & 63;
  const int row  = (blockIdx.x * blockDim.x + threadIdx.x) >> 6;  // global wave id
  const float* src; u16* dst; float* sq;
  if (row < MROWS) {
    src = feat + (size_t)row * DDIM; dst = Ab + (size_t)row * DDIM; sq = asq + row;
  } else {
    const int r = row - MROWS;
    src = cent + (size_t)r * DDIM;   dst = Bb + (size_t)r * DDIM;  sq = bsq + r;
  }
  float s = 0.f;
  #pragma unroll
  for (int h = 0; h < 2; ++h) {
    const int base = h * 512 + lane * 8;          // 8 consecutive floats per lane
    const float4v v0 = *(const float4v*)(src + base);
    const float4v v1 = *(const float4v*)(src + base + 4);
    ushort8 o;
    o[0] = f32_to_bf16_rne(v0[0]); o[1] = f32_to_bf16_rne(v0[1]);
    o[2] = f32_to_bf16_rne(v0[2]); o[3] = f32_to_bf16_rne(v0[3]);
    o[4] = f32_to_bf16_rne(v1[0]); o[5] = f32_to_bf16_rne(v1[1]);
    o[6] = f32_to_bf16_rne(v1[2]); o[7] = f32_to_bf16_rne(v1[3]);
    *(ushort8*)(dst + base) = o;                  // 16B store
    s += v0[0]*v0[0] + v0[1]*v0[1] + v0[2]*v0[2] + v0[3]*v0[3]
       + v1[0]*v1[0] + v1[1]*v1[1] + v1[2]*v1[2] + v1[3]*v1[3];
  }
  #pragma unroll
  for (int off = 32; off > 0; off >>= 1) s += __shfl_down(s, off, 64);
  if (lane == 0) *sq = s;
}

__device__ __forceinline__ void load_lds16(const u16* g, u16* l) {
  __builtin_amdgcn_global_load_lds(
      (const __attribute__((address_space(1))) u32*)g,
      (__attribute__((address_space(3))) u32*)l, 16, 0, 0);
}

// C = A[M,D] * B[K,D]^T, epilogue dist = asq[m] + bsq[n] - 2*C.
// LDS: row-major 128 rows x 64 bf16 (128 B = one full 32-bank sweep per row).
// 16B chunk kc of row r stored at physical chunk kc ^ (r&7): fragment reads
// (16 lanes, rows base+l16, fixed kc) spread 2-way per bank-group = free.
// Staging permutes the SOURCE chunk so the LDS destination stays
// lane-contiguous (global_load_lds requirement).
__global__ void dist_gemm(const u16* __restrict__ A, const u16* __restrict__ B,
                          const float* __restrict__ asq, const float* __restrict__ bsq,
                          float* __restrict__ out) {
  __shared__ __align__(16) u16 sA[BM * BK];   // 16 KB
  __shared__ __align__(16) u16 sB[BN * BK];   // 16 KB

  const int tid  = threadIdx.x;
  const int lane = tid & 63;
  const int wave = tid >> 6;        // 0..3
  const int quad = lane >> 4;       // 0..3
  const int l16  = lane & 15;
  const int sw   = l16 & 7;         // read-swizzle term (row&7 == l16&7)
  const int waveM = wave >> 1;      // 0..1
  const int waveN = wave & 1;       // 0..1

  // XCD-aware remap: all 16 col-blocks of a row-panel on one XCD.
  const int l   = blockIdx.y * gridDim.x + blockIdx.x;  // 0..2047
  const int xcd = l & 7;
  const int j   = l >> 3;                               // 0..255
  const int by  = xcd * 16 + (j >> 4);                  // row panel
  const int bx  = j & 15;                               // col panel (fastest)
  const int rowBase = by * BM;
  const int colBase = bx * BN;

  float4v acc[4][4];
  #pragma unroll
  for (int i = 0; i < 4; ++i)
    #pragma unroll
    for (int jj = 0; jj < 4; ++jj)
      acc[i][jj] = (float4v)(0.0f);

  for (int k0 = 0; k0 < DDIM; k0 += BK) {
    // 1024 chunks of 16B per tile; 4 chunks/thread/tile, lane-contiguous LDS.
    #pragma unroll
    for (int p = 0; p < 4; ++p) {
      const int c  = p * 256 + tid;             // LDS chunk index
      const int r  = c >> 3;                    // row 0..127
      const int kc = (c & 7) ^ (r & 7);         // swizzled global 16B-chunk
      load_lds16(A + (size_t)(rowBase + r) * DDIM + k0 + kc * 8, sA + c * 8);
      load_lds16(B + (size_t)(colBase + r) * DDIM + k0 + kc * 8, sB + c * 8);
    }
    __syncthreads();

    // Two k-groups of 32 within the 64-k tile: 32 MFMAs per barrier pair.
    #pragma unroll
    for (int g = 0; g < 2; ++g) {
      short8 a[4], b[4];
      const int kchunk = g * 4 + quad;          // logical 16B chunk in row
      #pragma unroll
      for (int i = 0; i < 4; ++i) {
        const int rowA = waveM * 64 + i * 16 + l16;
        a[i] = *(const short8*)&sA[(rowA * 8 + (kchunk ^ sw)) * 8];
        const int rowB = waveN * 64 + i * 16 + l16;
        b[i] = *(const short8*)&sB[(rowB * 8 + (kchunk ^ sw)) * 8];
      }
      #pragma unroll
      for (int i = 0; i < 4; ++i)
        #pragma unroll
        for (int jj = 0; jj < 4; ++jj)
          acc[i][jj] = __builtin_amdgcn_mfma_f32_16x16x32_bf16(a[i], b[jj], acc[i][jj], 0, 0, 0);
    }
    __syncthreads();
  }

  // Epilogue. C/D layout: col = lane&15, row = quad*4 + reg (m89/m91).
  #pragma unroll
  for (int i = 0; i < 4; ++i) {
    #pragma unroll
    for (int jj = 0; jj < 4; ++jj) {
      const int col = colBase + waveN * 64 + jj * 16 + l16;
      const float bs = bsq[col];
      #pragma unroll
      for (int r = 0; r < 4; ++r) {
        const int row = rowBase + waveM * 64 + i * 16 + quad * 4 + r;
        out[(size_t)row * NCOLS + col] = asq[row] + bs - 2.0f * acc[i][jj][r];
      }
    }
  }
}

// Safety net only (ws too small): plain fp32, correct but slow.
__global__ void naive_dist(const float* __restrict__ feat, const float* __restrict__ cent,
                           float* __restrict__ out) {
  const int k = blockIdx.x * 16 + threadIdx.x;
  const int n = blockIdx.y * 16 + threadIdx.y;
  const float* fp = feat + (size_t)n * DDIM;
  const float* cp = cent + (size_t)k * DDIM;
  float s = 0.f;
  for (int d = 0; d < DDIM; ++d) { float df = fp[d] - cp[d]; s += df * df; }
  out[(size_t)n * NCOLS + k] = s;
}

extern "C" void kernel_launch(void* const* d_in, const int* in_sizes, int n_in,
                              void* d_out, int out_size, void* d_ws, size_t ws_size,
                              hipStream_t stream) {
  const float* feat    = (const float*)d_in[0];   // [16384, 1024]
  const float* centers = (const float*)d_in[1];   // [2048, 1024]
  float* out = (float*)d_out;                     // [16384, 2048]

  const size_t offA   = 0;
  const size_t offB   = (size_t)MROWS * DDIM * 2;            // 33,554,432
  const size_t offAsq = offB + (size_t)NCOLS * DDIM * 2;     // 37,748,736
  const size_t offBsq = offAsq + (size_t)MROWS * 4;          // 37,814,272
  const size_t need   = offBsq + (size_t)NCOLS * 4;          // ~37.8 MB

  if (ws_size < need) {
    dim3 grid(NCOLS / 16, MROWS / 16), block(16, 16);
    naive_dist<<<grid, block, 0, stream>>>(feat, centers, out);
    return;
  }

  u16*   Ab  = (u16*)((char*)d_ws + offA);
  u16*   Bb  = (u16*)((char*)d_ws + offB);
  float* asq = (float*)((char*)d_ws + offAsq);
  float* bsq = (float*)((char*)d_ws + offBsq);

  prep_all<<<(MROWS + NCOLS) / 4, 256, 0, stream>>>(feat, centers, Ab, Bb, asq, bsq);

  dim3 grid(NCOLS / BN, MROWS / BM);   // (16, 128)
  dist_gemm<<<grid, 256, 0, stream>>>(Ab, Bb, asq, bsq, out);
}